// Round 10
// baseline (700.843 us; speedup 1.0000x reference)
//
#include <hip/hip_runtime.h>
#include <hip/hip_bf16.h>

#define T_ 16
#define B_ 8
#define CIN 768
#define D_ 256
#define K_ 64
#define HW 784
#define W_ 28

typedef short short8 __attribute__((ext_vector_type(8)));
typedef short short4v __attribute__((ext_vector_type(4)));
typedef float floatx4 __attribute__((ext_vector_type(4)));
typedef unsigned short ushort_t;

// ---------------- bf16 split helpers ----------------
__device__ __forceinline__ unsigned short f2bf(float x) {
    union { float f; unsigned u; } v; v.f = x;
    unsigned u = v.u;
    unsigned r = (u + 0x7fffu + ((u >> 16) & 1u)) >> 16;   // RNE
    return (unsigned short)r;
}
__device__ __forceinline__ float bf2f(unsigned short h) {
    union { unsigned u; float f; } v; v.u = ((unsigned)h) << 16; return v.f;
}

// ---------------- block reduce helper ----------------
__device__ __forceinline__ float block_reduce_sum_256(float v) {
    for (int off = 32; off > 0; off >>= 1) v += __shfl_down(v, off, 64);
    __shared__ float red[4];
    __shared__ float tot;
    int lane = threadIdx.x & 63, wid = threadIdx.x >> 6;
    if (lane == 0) red[wid] = v;
    __syncthreads();
    if (threadIdx.x == 0) tot = red[0] + red[1] + red[2] + red[3];
    __syncthreads();
    return tot;
}

// ---------------- weight split (once per launch) ----------------
__global__ __launch_bounds__(256) void cvt_weights(
    const float* __restrict__ rw, const float* __restrict__ sw,
    const float* __restrict__ Uz, const float* __restrict__ Ur,
    const float* __restrict__ Uh,
    ushort_t* __restrict__ whi, ushort_t* __restrict__ wlo,
    ushort_t* __restrict__ shi, ushort_t* __restrict__ slo,
    ushort_t* __restrict__ azh, ushort_t* __restrict__ azl,
    ushort_t* __restrict__ ahh, ushort_t* __restrict__ ahl)
{
    int i = blockIdx.x * 256 + threadIdx.x;
    const int nR = D_ * CIN;           // 196608
    const int nS = K_ * D_;            // 16384
    const int nZR = 128 * 576;         // 73728
    const int nH = 64 * 576;           // 36864
    if (i < nR) {
        float x = rw[i];
        unsigned short h = f2bf(x);
        whi[i] = h; wlo[i] = f2bf(x - bf2f(h));
    } else if (i < nR + nS) {
        int j = i - nR;
        float x = sw[j];
        unsigned short h = f2bf(x);
        shi[j] = h; slo[j] = f2bf(x - bf2f(h));
    } else if (i < nR + nS + nZR) {
        int j = i - nR - nS;
        int row = j / 576, kk = j - row * 576;
        int tap = kk >> 6, c = kk & 63;
        const float* U = (row < 64) ? Uz : Ur;
        float x = U[(((size_t)(row & 63)) * 64 + c) * 9 + tap];
        unsigned short h = f2bf(x);
        azh[j] = h; azl[j] = f2bf(x - bf2f(h));
    } else if (i < nR + nS + nZR + nH) {
        int j = i - nR - nS - nZR;
        int row = j / 576, kk = j - row * 576;
        int tap = kk >> 6, c = kk & 63;
        float x = Uh[(((size_t)row) * 64 + c) * 9 + tap];
        unsigned short h = f2bf(x);
        ahh[j] = h; ahl[j] = f2bf(x - bf2f(h));
    }
}

// ---------------- 1x1 conv as split-bf16 MFMA GEMM ----------------
// Reg-dbuf B pipeline; wave owns MI m-frags x all 7 n-frags.
// grid (7, MTOT/BM, 128), 256 thr.
template<int MTOT, int BM, int KD, int MINW>
__global__ __launch_bounds__(256, MINW) void mfma_conv1x1(
    const float* __restrict__ X, const ushort_t* __restrict__ Whi,
    const ushort_t* __restrict__ Wlo, const float* __restrict__ bias,
    float* __restrict__ Out)
{
    const int nt = blockIdx.x, mt = blockIdx.y, bt = blockIdx.z;
    const int p0 = nt * 112, m0 = mt * BM;
    const int tid = threadIdx.x, lane = tid & 63, wv = tid >> 6;
    const int li = lane & 15, koff = (lane >> 4) * 8;
    constexpr int MI = BM / 64;                 // 4 (redu) or 1 (share)
    constexpr int NKS = KD / 32;                // even
    const float* Xb = X + (size_t)bt * KD * HW;
    float* Ob = Out + (size_t)bt * MTOT * HW;

    __shared__ ushort_t lB[2][112 * 40];        // [hi/lo][pp][k0..31], pad 40

    floatx4 acc[MI][7];
#pragma unroll
    for (int a = 0; a < MI; ++a)
#pragma unroll
        for (int b = 0; b < 7; ++b) acc[a][b] = (floatx4){0.f, 0.f, 0.f, 0.f};

    const int mbase = m0 + wv * (MI * 16);

    const int u0j = tid / 112, u0p = tid - u0j * 112;
    const bool u1v = tid < 192;
    const int u1j = (tid + 256) / 112, u1p = (tid + 256) - u1j * 112;

    float b0[16], b1[16];
    short8 ahi[MI], alo[MI];

    auto loadB = [&](int k0, float* bb) {
        const float* xp0 = Xb + (size_t)(k0 + u0j * 8) * HW + p0 + u0p;
#pragma unroll
        for (int c = 0; c < 8; ++c) bb[c] = xp0[(size_t)c * HW];
        if (u1v) {
            const float* xp1 = Xb + (size_t)(k0 + u1j * 8) * HW + p0 + u1p;
#pragma unroll
            for (int c = 0; c < 8; ++c) bb[8 + c] = xp1[(size_t)c * HW];
        }
    };
    auto writeB = [&](const float* bb) {
        short8 vh, vl;
#pragma unroll
        for (int c = 0; c < 8; ++c) {
            unsigned short h = f2bf(bb[c]);
            vh[c] = (short)h; vl[c] = (short)f2bf(bb[c] - bf2f(h));
        }
        *(short8*)&lB[0][u0p * 40 + u0j * 8] = vh;
        *(short8*)&lB[1][u0p * 40 + u0j * 8] = vl;
        if (u1v) {
#pragma unroll
            for (int c = 0; c < 8; ++c) {
                unsigned short h = f2bf(bb[8 + c]);
                vh[c] = (short)h; vl[c] = (short)f2bf(bb[8 + c] - bf2f(h));
            }
            *(short8*)&lB[0][u1p * 40 + u1j * 8] = vh;
            *(short8*)&lB[1][u1p * 40 + u1j * 8] = vl;
        }
    };
    auto loadA = [&](int k0) {
#pragma unroll
        for (int mi = 0; mi < MI; ++mi) {
            int m = mbase + mi * 16 + li;
            ahi[mi] = *(const short8*)(Whi + (size_t)m * KD + k0 + koff);
            alo[mi] = *(const short8*)(Wlo + (size_t)m * KD + k0 + koff);
        }
    };
    auto domfma = [&]() {
#pragma unroll
        for (int ni = 0; ni < 7; ++ni) {
            int n = ni * 16 + li;
            short8 bhi = *(const short8*)&lB[0][n * 40 + koff];
            short8 blo = *(const short8*)&lB[1][n * 40 + koff];
#pragma unroll
            for (int mi = 0; mi < MI; ++mi) {
                acc[mi][ni] = __builtin_amdgcn_mfma_f32_16x16x32_bf16(ahi[mi], bhi, acc[mi][ni], 0, 0, 0);
                acc[mi][ni] = __builtin_amdgcn_mfma_f32_16x16x32_bf16(ahi[mi], blo, acc[mi][ni], 0, 0, 0);
                acc[mi][ni] = __builtin_amdgcn_mfma_f32_16x16x32_bf16(alo[mi], bhi, acc[mi][ni], 0, 0, 0);
            }
        }
    };

    loadB(0, b0);
    for (int ks = 0; ks < NKS; ks += 2) {
        loadA(ks * 32);
        writeB(b0);
        __syncthreads();
        if (ks + 1 < NKS) loadB((ks + 1) * 32, b1);
        domfma();
        __syncthreads();
        loadA((ks + 1) * 32);
        writeB(b1);
        __syncthreads();
        if (ks + 2 < NKS) loadB((ks + 2) * 32, b0);
        domfma();
        __syncthreads();
    }

#pragma unroll
    for (int mi = 0; mi < MI; ++mi) {
        int m0g = mbase + mi * 16 + ((lane >> 4) << 2);
#pragma unroll
        for (int ni = 0; ni < 7; ++ni) {
            int p = p0 + ni * 16 + li;
#pragma unroll
            for (int r = 0; r < 4; ++r)
                Ob[(size_t)(m0g + r) * HW + p] = acc[mi][ni][r] + bias[m0g + r];
        }
    }
}

// ---------------- fused GRU step (r5 structure + reg-pipelining freedom) ----------------
// launch_bounds(512,1): grid 224 blocks -> 1 block/CU anyway; 256-VGPR budget
// lets the compiler software-pipeline the per-tap weight loads.
// wxb epilogue operands prefetched to registers before each tap loop.
__global__ __launch_bounds__(512, 1) void gru_step(
    const ushort_t* __restrict__ hRhi, const ushort_t* __restrict__ hRlo,
    ushort_t* __restrict__ hWhi, ushort_t* __restrict__ hWlo,
    const ushort_t* __restrict__ azh, const ushort_t* __restrict__ azl,
    const ushort_t* __restrict__ ahh, const ushort_t* __restrict__ ahl,
    const float* __restrict__ wxb, float* __restrict__ hs_t, int t)
{
    const int y0 = blockIdx.x, b = blockIdx.y;
    const int tid = threadIdx.x, lane = tid & 63, wv = tid >> 6;
    const int li = lane & 15, koff8 = (lane >> 4) * 8, kq = (lane >> 4) * 4;

    __shared__ ushort_t Hhi[5 * 30 * 72], Hlo[5 * 30 * 72];  // h rows y0-2..y0+2
    __shared__ ushort_t Rhi[3 * 30 * 72], Rlo[3 * 30 * 72];  // r*h rows y0-1..y0+1
    __shared__ float zs[28 * 68];                            // z[col][k]

    {
        const ushort_t* gh = hRhi + (size_t)b * HW * 64;
        const ushort_t* gl = hRlo + (size_t)b * HW * 64;
        for (int e = tid; e < 1200; e += 512) {
            int r = e / 240, rem = e - r * 240;
            int lx = rem >> 3, j = rem & 7;
            int gy = y0 - 2 + r, gx = lx - 1;
            short8 vh = {0,0,0,0,0,0,0,0}, vl = {0,0,0,0,0,0,0,0};
            if (gy >= 0 && gy < 28 && gx >= 0 && gx < 28) {
                size_t go = ((size_t)(gy * 28 + gx)) * 64 + j * 8;
                vh = *(const short8*)(gh + go);
                vl = *(const short8*)(gl + go);
            }
            int lo = (r * 30 + lx) * 72 + j * 8;
            *(short8*)&Hhi[lo] = vh;
            *(short8*)&Hlo[lo] = vl;
        }
        short8 z8 = {0,0,0,0,0,0,0,0};
        for (int e = tid; e < 1620; e += 512) {
            if (e < 810) *(short8*)&Rhi[e * 8] = z8;
            else         *(short8*)&Rlo[(e - 810) * 8] = z8;
        }
    }
    __syncthreads();

    const float* wx = wxb + ((size_t)(b * T_ + t) * K_) * HW;
    const int c0 = li;
    const int c1 = (li < 12) ? 16 + li : 0;

    if (wv < 4) {
        // ---- z gate
        const int kb = wv * 16;
        const int kb4 = kb + kq;
        const ushort_t* Ah = azh + (size_t)(kb + li) * 576;
        const ushort_t* Al = azl + (size_t)(kb + li) * 576;

        // prefetch wx operands (independent of LDS/MFMA)
        float wz[2][4];
#pragma unroll
        for (int cf = 0; cf < 2; ++cf) {
            int c = cf * 16 + li;
#pragma unroll
            for (int r = 0; r < 4; ++r)
                wz[cf][r] = (c < 28) ? wx[(size_t)(kb4 + r) * HW + y0 * 28 + c] : 0.f;
        }

        floatx4 az[2];
        az[0] = (floatx4){0.f,0.f,0.f,0.f}; az[1] = (floatx4){0.f,0.f,0.f,0.f};
#pragma unroll
        for (int tap = 0; tap < 9; ++tap) {
            const int dy = tap / 3, dx = tap - dy * 3;
#pragma unroll
            for (int ch = 0; ch < 2; ++ch) {
                short8 whi_ = *(const short8*)(Ah + tap * 64 + ch * 32 + koff8);
                short8 wlo_ = *(const short8*)(Al + tap * 64 + ch * 32 + koff8);
                int cb = ch * 32 + koff8;
                int o0 = ((dy + 1) * 30 + c0 + dx) * 72 + cb;
                int o1 = ((dy + 1) * 30 + c1 + dx) * 72 + cb;
                short8 bh0 = *(const short8*)&Hhi[o0];
                short8 bl0 = *(const short8*)&Hlo[o0];
                short8 bh1 = *(const short8*)&Hhi[o1];
                short8 bl1 = *(const short8*)&Hlo[o1];
                az[0] = __builtin_amdgcn_mfma_f32_16x16x32_bf16(whi_, bh0, az[0], 0, 0, 0);
                az[0] = __builtin_amdgcn_mfma_f32_16x16x32_bf16(whi_, bl0, az[0], 0, 0, 0);
                az[0] = __builtin_amdgcn_mfma_f32_16x16x32_bf16(wlo_, bh0, az[0], 0, 0, 0);
                az[1] = __builtin_amdgcn_mfma_f32_16x16x32_bf16(whi_, bh1, az[1], 0, 0, 0);
                az[1] = __builtin_amdgcn_mfma_f32_16x16x32_bf16(whi_, bl1, az[1], 0, 0, 0);
                az[1] = __builtin_amdgcn_mfma_f32_16x16x32_bf16(wlo_, bh1, az[1], 0, 0, 0);
            }
        }
#pragma unroll
        for (int cf = 0; cf < 2; ++cf) {
            int c = cf * 16 + li;
            if (c < 28) {
                floatx4 zv;
#pragma unroll
                for (int r = 0; r < 4; ++r)
                    zv[r] = 1.f / (1.f + __expf(-(wz[cf][r] + az[cf][r])));
                *(floatx4*)&zs[c * 68 + kb4] = zv;
            }
        }
    } else {
        // ---- r gate rows y0-1..y0+1 -> r*h
        const int kb = (wv - 4) * 16;
        const int kb4 = kb + kq;
        const ushort_t* Ah = azh + (size_t)(64 + kb + li) * 576;
        const ushort_t* Al = azl + (size_t)(64 + kb + li) * 576;

        // prefetch wx operands for all 3 rows
        float wr[3][2][4];
#pragma unroll
        for (int rr = 0; rr < 3; ++rr) {
            int gy = y0 - 1 + rr;
#pragma unroll
            for (int cf = 0; cf < 2; ++cf) {
                int c = cf * 16 + li;
                bool v = (gy >= 0 && gy < 28 && c < 28);
#pragma unroll
                for (int r = 0; r < 4; ++r)
                    wr[rr][cf][r] = v ? wx[(size_t)(kb4 + r) * HW + gy * 28 + c] : 0.f;
            }
        }

        floatx4 ar[3][2];
#pragma unroll
        for (int i = 0; i < 3; ++i) {
            ar[i][0] = (floatx4){0.f,0.f,0.f,0.f};
            ar[i][1] = (floatx4){0.f,0.f,0.f,0.f};
        }
#pragma unroll
        for (int tap = 0; tap < 9; ++tap) {
            const int dy = tap / 3, dx = tap - dy * 3;
#pragma unroll
            for (int ch = 0; ch < 2; ++ch) {
                short8 whi_ = *(const short8*)(Ah + tap * 64 + ch * 32 + koff8);
                short8 wlo_ = *(const short8*)(Al + tap * 64 + ch * 32 + koff8);
                int cb = ch * 32 + koff8;
#pragma unroll
                for (int rr = 0; rr < 3; ++rr) {
                    int o0 = ((rr + dy) * 30 + c0 + dx) * 72 + cb;
                    int o1 = ((rr + dy) * 30 + c1 + dx) * 72 + cb;
                    short8 bh0 = *(const short8*)&Hhi[o0];
                    short8 bl0 = *(const short8*)&Hlo[o0];
                    short8 bh1 = *(const short8*)&Hhi[o1];
                    short8 bl1 = *(const short8*)&Hlo[o1];
                    ar[rr][0] = __builtin_amdgcn_mfma_f32_16x16x32_bf16(whi_, bh0, ar[rr][0], 0, 0, 0);
                    ar[rr][0] = __builtin_amdgcn_mfma_f32_16x16x32_bf16(whi_, bl0, ar[rr][0], 0, 0, 0);
                    ar[rr][0] = __builtin_amdgcn_mfma_f32_16x16x32_bf16(wlo_, bh0, ar[rr][0], 0, 0, 0);
                    ar[rr][1] = __builtin_amdgcn_mfma_f32_16x16x32_bf16(whi_, bh1, ar[rr][1], 0, 0, 0);
                    ar[rr][1] = __builtin_amdgcn_mfma_f32_16x16x32_bf16(whi_, bl1, ar[rr][1], 0, 0, 0);
                    ar[rr][1] = __builtin_amdgcn_mfma_f32_16x16x32_bf16(wlo_, bh1, ar[rr][1], 0, 0, 0);
                }
            }
        }
#pragma unroll
        for (int rr = 0; rr < 3; ++rr) {
            int gy = y0 - 1 + rr;
            if (gy < 0 || gy >= 28) continue;
#pragma unroll
            for (int cf = 0; cf < 2; ++cf) {
                int c = cf * 16 + li;
                if (c >= 28) continue;
                short4v ph = *(const short4v*)&Hhi[((rr + 1) * 30 + c + 1) * 72 + kb4];
                short4v pl = *(const short4v*)&Hlo[((rr + 1) * 30 + c + 1) * 72 + kb4];
                short4v vh, vl;
#pragma unroll
                for (int r = 0; r < 4; ++r) {
                    float rv = 1.f / (1.f + __expf(-(wr[rr][cf][r] + ar[rr][cf][r])));
                    float hv = bf2f((unsigned short)ph[r]) + bf2f((unsigned short)pl[r]);
                    float rh = rv * hv;
                    unsigned short h = f2bf(rh);
                    vh[r] = (short)h; vl[r] = (short)f2bf(rh - bf2f(h));
                }
                *(short4v*)&Rhi[(rr * 30 + c + 1) * 72 + kb4] = vh;
                *(short4v*)&Rlo[(rr * 30 + c + 1) * 72 + kb4] = vl;
            }
        }
    }
    __syncthreads();

    if (wv < 4) {
        // ---- candidate conv + state update
        const int kb = wv * 16;
        const int kb4 = kb + kq;
        const ushort_t* Ah = ahh + (size_t)(kb + li) * 576;
        const ushort_t* Al = ahl + (size_t)(kb + li) * 576;

        float wc[2][4];
#pragma unroll
        for (int cf = 0; cf < 2; ++cf) {
            int c = cf * 16 + li;
#pragma unroll
            for (int r = 0; r < 4; ++r)
                wc[cf][r] = (c < 28) ? wx[(size_t)(kb4 + r) * HW + y0 * 28 + c] : 0.f;
        }

        floatx4 ac[2];
        ac[0] = (floatx4){0.f,0.f,0.f,0.f}; ac[1] = (floatx4){0.f,0.f,0.f,0.f};
#pragma unroll
        for (int tap = 0; tap < 9; ++tap) {
            const int dy = tap / 3, dx = tap - dy * 3;
#pragma unroll
            for (int ch = 0; ch < 2; ++ch) {
                short8 whi_ = *(const short8*)(Ah + tap * 64 + ch * 32 + koff8);
                short8 wlo_ = *(const short8*)(Al + tap * 64 + ch * 32 + koff8);
                int cb = ch * 32 + koff8;
                int o0 = (dy * 30 + c0 + dx) * 72 + cb;
                int o1 = (dy * 30 + c1 + dx) * 72 + cb;
                short8 bh0 = *(const short8*)&Rhi[o0];
                short8 bl0 = *(const short8*)&Rlo[o0];
                short8 bh1 = *(const short8*)&Rhi[o1];
                short8 bl1 = *(const short8*)&Rlo[o1];
                ac[0] = __builtin_amdgcn_mfma_f32_16x16x32_bf16(whi_, bh0, ac[0], 0, 0, 0);
                ac[0] = __builtin_amdgcn_mfma_f32_16x16x32_bf16(whi_, bl0, ac[0], 0, 0, 0);
                ac[0] = __builtin_amdgcn_mfma_f32_16x16x32_bf16(wlo_, bh0, ac[0], 0, 0, 0);
                ac[1] = __builtin_amdgcn_mfma_f32_16x16x32_bf16(whi_, bh1, ac[1], 0, 0, 0);
                ac[1] = __builtin_amdgcn_mfma_f32_16x16x32_bf16(whi_, bl1, ac[1], 0, 0, 0);
                ac[1] = __builtin_amdgcn_mfma_f32_16x16x32_bf16(wlo_, bh1, ac[1], 0, 0, 0);
            }
        }
        float* hsb = hs_t + (size_t)b * K_ * HW;
#pragma unroll
        for (int cf = 0; cf < 2; ++cf) {
            int c = cf * 16 + li;
            if (c >= 28) continue;
            int p = y0 * 28 + c;
            floatx4 zv = *(const floatx4*)&zs[c * 68 + kb4];
            short4v ph = *(const short4v*)&Hhi[(2 * 30 + c + 1) * 72 + kb4];
            short4v pl = *(const short4v*)&Hlo[(2 * 30 + c + 1) * 72 + kb4];
            short4v vh, vl;
#pragma unroll
            for (int r = 0; r < 4; ++r) {
                int k = kb4 + r;
                float xv = wc[cf][r] + ac[cf][r];
                float e2 = __expf(2.f * xv);
                float th = 1.f - 2.f / (e2 + 1.f);
                float hp = bf2f((unsigned short)ph[r]) + bf2f((unsigned short)pl[r]);
                float hn = (1.f - zv[r]) * th + zv[r] * hp;
                hsb[(size_t)k * HW + p] = hn;
                unsigned short h = f2bf(hn);
                vh[r] = (short)h; vl[r] = (short)f2bf(hn - bf2f(h));
            }
            size_t o = ((size_t)(b * HW) + p) * 64 + kb4;
            *(short4v*)(hWhi + o) = vh;
            *(short4v*)(hWlo + o) = vl;
        }
    }
}

// ---------------- softmax over k (in place on hs) ----------------
__global__ __launch_bounds__(256) void softmax_k(float* __restrict__ hs)
{
    int q = blockIdx.x;
    int py = blockIdx.y;
    float* base = hs + (size_t)q * K_ * HW;
    for (int p = py * 392 + threadIdx.x; p < (py + 1) * 392 && p < HW; p += 256) {
        float v[64];
        float m = -1e30f;
#pragma unroll
        for (int k = 0; k < 64; ++k) {
            v[k] = base[(size_t)k * HW + p];
            m = fmaxf(m, v[k]);
        }
        float s = 0.f;
#pragma unroll
        for (int k = 0; k < 64; ++k) {
            v[k] = __expf(v[k] - m);
            s += v[k];
        }
        float inv = 1.f / s;
#pragma unroll
        for (int k = 0; k < 64; ++k)
            base[(size_t)k * HW + p] = v[k] * inv;
    }
}

// ---------------- VLAD: per-(b,t) outer-product GEMM + fused a_sum ----------------
__global__ __launch_bounds__(256) void vlad_k(const float* __restrict__ assign,
    const float* __restrict__ xr, float* __restrict__ vladt,
    float* __restrict__ asum_bt)
{
    int dt = blockIdx.x, t = blockIdx.y, b = blockIdx.z;
    int q = t * B_ + b, bt = b * T_ + t, d0 = dt * 64;
    const float* ab = assign + (size_t)q * K_ * HW;
    const float* xb = xr + (size_t)bt * D_ * HW;
    __shared__ float As[16][68];
    __shared__ float Xs[16][68];
    int tx = threadIdx.x & 15, ty = threadIdx.x >> 4;
    float acc[4][4] = {{0.f}};
    float pacc[4] = {0.f, 0.f, 0.f, 0.f};

    for (int p0 = 0; p0 < HW; p0 += 16) {
#pragma unroll
        for (int it = 0; it < 4; ++it) {
            int e = threadIdx.x + it * 256;
            int row = e >> 4, pp = e & 15;
            float av_ = ab[(size_t)row * HW + p0 + pp];
            As[pp][row] = av_;
            if (dt == 0) pacc[it] += av_;
            Xs[pp][row] = xb[(size_t)(d0 + row) * HW + p0 + pp];
        }
        __syncthreads();
#pragma unroll
        for (int pp = 0; pp < 16; ++pp) {
            float4 a = *(const float4*)&As[pp][ty * 4];
            float4 xv = *(const float4*)&Xs[pp][tx * 4];
            float av[4] = {a.x, a.y, a.z, a.w};
            float xvv[4] = {xv.x, xv.y, xv.z, xv.w};
#pragma unroll
            for (int r = 0; r < 4; ++r)
#pragma unroll
                for (int s = 0; s < 4; ++s)
                    acc[r][s] = fmaf(av[r], xvv[s], acc[r][s]);
        }
        __syncthreads();
    }
#pragma unroll
    for (int r = 0; r < 4; ++r) {
        int k = ty * 4 + r;
        float4 o = {acc[r][0], acc[r][1], acc[r][2], acc[r][3]};
        *(float4*)&vladt[((size_t)bt * K_ + k) * D_ + d0 + tx * 4] = o;
    }
    if (dt == 0) {
#pragma unroll
        for (int it = 0; it < 4; ++it) {
            float s = pacc[it];
#pragma unroll
            for (int off = 1; off < 16; off <<= 1) s += __shfl_xor(s, off, 16);
            if (tx == 0) asum_bt[(size_t)bt * 64 + ty + it * 16] = s;
        }
    }
}

// ---------------- reduce over t, subtract a_sum*centers, intra-norm ----------------
__global__ __launch_bounds__(256) void norm1_k(const float* __restrict__ vladt,
    const float* __restrict__ asum_bt, const float* __restrict__ centers,
    float* __restrict__ out)
{
    int bid = blockIdx.x; int b = bid >> 6, k = bid & 63; int d = threadIdx.x;
    float acc = 0.f;
#pragma unroll
    for (int t = 0; t < T_; ++t)
        acc += vladt[(((size_t)b * T_ + t) * K_ + k) * D_ + d];
    float asum = 0.f;
#pragma unroll
    for (int t = 0; t < T_; ++t)
        asum += asum_bt[(size_t)(b * T_ + t) * 64 + k];
    acc -= asum * centers[(size_t)k * D_ + d];
    float ss = block_reduce_sum_256(acc * acc);
    float n = fmaxf(sqrtf(ss), 1e-12f);
    out[((size_t)b * K_ + k) * D_ + d] = acc / n;
}

// ---------------- global L2 norm per b ----------------
__global__ __launch_bounds__(256) void norm2_k(float* __restrict__ out)
{
    int b = blockIdx.x;
    float* v = out + (size_t)b * (K_ * D_);
    float s = 0.f;
    for (int i = threadIdx.x; i < K_ * D_; i += 256) {
        float x = v[i];
        s = fmaf(x, x, s);
    }
    float tot = block_reduce_sum_256(s);
    float n = fmaxf(sqrtf(tot), 1e-12f);
    for (int i = threadIdx.x; i < K_ * D_; i += 256) v[i] = v[i] / n;
}

// ---------------- launch ----------------
extern "C" void kernel_launch(void* const* d_in, const int* in_sizes, int n_in,
                              void* d_out, int out_size, void* d_ws, size_t ws_size,
                              hipStream_t stream)
{
    const float* x       = (const float*)d_in[0];
    const float* redu_w  = (const float*)d_in[1];
    const float* redu_b  = (const float*)d_in[2];
    const float* share_w = (const float*)d_in[3];
    const float* share_b = (const float*)d_in[4];
    const float* Uz      = (const float*)d_in[5];
    const float* Ur      = (const float*)d_in[6];
    const float* Uh      = (const float*)d_in[7];
    const float* centers = (const float*)d_in[8];

    float* ws = (float*)d_ws;
    const size_t SZ_XR   = (size_t)128 * D_ * HW;       // 25,690,112
    const size_t SZ_WXB  = (size_t)128 * K_ * HW;       //  6,422,528
    const size_t SZ_HS   = (size_t)T_ * B_ * K_ * HW;   //  6,422,528
    const size_t SZ_PLANE= (size_t)B_ * K_ * HW;        //    401,408

    float* xr     = ws;
    float* wxb    = xr + SZ_XR;
    float* hs     = wxb + SZ_WXB;
    float* asum_bt= hs + SZ_HS;              // 8192 floats
    float* wsplit = asum_bt + 8192;          // split weights (323,584 floats)
    float* area   = wsplit + 323584;         // union: vladt | GRU split state

    ushort_t* whi = (ushort_t*)wsplit;            // 196608
    ushort_t* wlo = whi + 196608;
    ushort_t* shi = wlo + 196608;                 // 16384
    ushort_t* slo = shi + 16384;
    ushort_t* azh = slo + 16384;                  // 73728
    ushort_t* azl = azh + 73728;
    ushort_t* ahh = azl + 73728;                  // 36864
    ushort_t* ahl = ahh + 36864;

    float* vladt = area;                          // 2,097,152 floats (after GRU)
    ushort_t* st = (ushort_t*)area;               // GRU double-buffered state
    ushort_t* h0hi = st;
    ushort_t* h0lo = st + SZ_PLANE;
    ushort_t* h1hi = st + 2 * SZ_PLANE;
    ushort_t* h1lo = st + 3 * SZ_PLANE;

    hipMemsetAsync(h0hi, 0, 2 * SZ_PLANE * sizeof(ushort_t), stream);

    cvt_weights<<<dim3((D_ * CIN + K_ * D_ + 128 * 576 + 64 * 576 + 255) / 256),
                  256, 0, stream>>>(redu_w, share_w, Uz, Ur, Uh,
                                    whi, wlo, shi, slo, azh, azl, ahh, ahl);

    // 1) channel reduction (split-bf16 MFMA, BM=256: single B-read)
    mfma_conv1x1<256, 256, CIN, 2><<<dim3(7, 1, 128), 256, 0, stream>>>(x, whi, wlo, redu_b, xr);
    // 2) assignment logits
    mfma_conv1x1<64, 64, D_, 4><<<dim3(7, 1, 128), 256, 0, stream>>>(xr, shi, slo, share_b, wxb);

    // 3) ConvGRU: one fused dispatch per timestep
    for (int t = 0; t < T_; ++t) {
        const ushort_t* rh_ = (t & 1) ? h1hi : h0hi;
        const ushort_t* rl_ = (t & 1) ? h1lo : h0lo;
        ushort_t* wh_ = (t & 1) ? h0hi : h1hi;
        ushort_t* wl_ = (t & 1) ? h0lo : h1lo;
        gru_step<<<dim3(28, 8), 512, 0, stream>>>(rh_, rl_, wh_, wl_,
                                                  azh, azl, ahh, ahl,
                                                  wxb, hs + (size_t)t * SZ_PLANE, t);
    }

    // 4) softmax over centers
    softmax_k<<<dim3(128, 2), 256, 0, stream>>>(hs);

    // 5) VLAD aggregation (+fused a_sum) + norms
    vlad_k<<<dim3(4, 16, 8), 256, 0, stream>>>(hs, xr, vladt, asum_bt);
    norm1_k<<<512, 256, 0, stream>>>(vladt, asum_bt, centers, (float*)d_out);
    norm2_k<<<8, 256, 0, stream>>>((float*)d_out);
}

// Round 11
// 647.648 us; speedup vs baseline: 1.0821x; 1.0821x over previous
//
#include <hip/hip_runtime.h>
#include <hip/hip_bf16.h>

#define T_ 16
#define B_ 8
#define CIN 768
#define D_ 256
#define K_ 64
#define HW 784
#define W_ 28

typedef short short8 __attribute__((ext_vector_type(8)));
typedef short short4v __attribute__((ext_vector_type(4)));
typedef float floatx4 __attribute__((ext_vector_type(4)));
typedef unsigned short ushort_t;

// ---------------- bf16 split helpers ----------------
__device__ __forceinline__ unsigned short f2bf(float x) {
    union { float f; unsigned u; } v; v.f = x;
    unsigned u = v.u;
    unsigned r = (u + 0x7fffu + ((u >> 16) & 1u)) >> 16;   // RNE
    return (unsigned short)r;
}
__device__ __forceinline__ float bf2f(unsigned short h) {
    union { unsigned u; float f; } v; v.u = ((unsigned)h) << 16; return v.f;
}

// ---------------- block reduce helper ----------------
__device__ __forceinline__ float block_reduce_sum_256(float v) {
    for (int off = 32; off > 0; off >>= 1) v += __shfl_down(v, off, 64);
    __shared__ float red[4];
    __shared__ float tot;
    int lane = threadIdx.x & 63, wid = threadIdx.x >> 6;
    if (lane == 0) red[wid] = v;
    __syncthreads();
    if (threadIdx.x == 0) tot = red[0] + red[1] + red[2] + red[3];
    __syncthreads();
    return tot;
}

// ---------------- weight split (once per launch) ----------------
__global__ __launch_bounds__(256) void cvt_weights(
    const float* __restrict__ rw, const float* __restrict__ sw,
    const float* __restrict__ Uz, const float* __restrict__ Ur,
    const float* __restrict__ Uh,
    ushort_t* __restrict__ whi, ushort_t* __restrict__ wlo,
    ushort_t* __restrict__ shi, ushort_t* __restrict__ slo,
    ushort_t* __restrict__ azh, ushort_t* __restrict__ azl,
    ushort_t* __restrict__ ahh, ushort_t* __restrict__ ahl)
{
    int i = blockIdx.x * 256 + threadIdx.x;
    const int nR = D_ * CIN;           // 196608
    const int nS = K_ * D_;            // 16384
    const int nZR = 128 * 576;         // 73728
    const int nH = 64 * 576;           // 36864
    if (i < nR) {
        float x = rw[i];
        unsigned short h = f2bf(x);
        whi[i] = h; wlo[i] = f2bf(x - bf2f(h));
    } else if (i < nR + nS) {
        int j = i - nR;
        float x = sw[j];
        unsigned short h = f2bf(x);
        shi[j] = h; slo[j] = f2bf(x - bf2f(h));
    } else if (i < nR + nS + nZR) {
        int j = i - nR - nS;
        int row = j / 576, kk = j - row * 576;
        int tap = kk >> 6, c = kk & 63;
        const float* U = (row < 64) ? Uz : Ur;
        float x = U[(((size_t)(row & 63)) * 64 + c) * 9 + tap];
        unsigned short h = f2bf(x);
        azh[j] = h; azl[j] = f2bf(x - bf2f(h));
    } else if (i < nR + nS + nZR + nH) {
        int j = i - nR - nS - nZR;
        int row = j / 576, kk = j - row * 576;
        int tap = kk >> 6, c = kk & 63;
        float x = Uh[(((size_t)row) * 64 + c) * 9 + tap];
        unsigned short h = f2bf(x);
        ahh[j] = h; ahl[j] = f2bf(x - bf2f(h));
    }
}

// ---------------- 1x1 conv as split-bf16 MFMA GEMM (r10 proven, BM=256) ----------------
template<int MTOT, int BM, int KD, int MINW>
__global__ __launch_bounds__(256, MINW) void mfma_conv1x1(
    const float* __restrict__ X, const ushort_t* __restrict__ Whi,
    const ushort_t* __restrict__ Wlo, const float* __restrict__ bias,
    float* __restrict__ Out)
{
    const int nt = blockIdx.x, mt = blockIdx.y, bt = blockIdx.z;
    const int p0 = nt * 112, m0 = mt * BM;
    const int tid = threadIdx.x, lane = tid & 63, wv = tid >> 6;
    const int li = lane & 15, koff = (lane >> 4) * 8;
    constexpr int MI = BM / 64;
    constexpr int NKS = KD / 32;
    const float* Xb = X + (size_t)bt * KD * HW;
    float* Ob = Out + (size_t)bt * MTOT * HW;

    __shared__ ushort_t lB[2][112 * 40];

    floatx4 acc[MI][7];
#pragma unroll
    for (int a = 0; a < MI; ++a)
#pragma unroll
        for (int b = 0; b < 7; ++b) acc[a][b] = (floatx4){0.f, 0.f, 0.f, 0.f};

    const int mbase = m0 + wv * (MI * 16);

    const int u0j = tid / 112, u0p = tid - u0j * 112;
    const bool u1v = tid < 192;
    const int u1j = (tid + 256) / 112, u1p = (tid + 256) - u1j * 112;

    float b0[16], b1[16];
    short8 ahi[MI], alo[MI];

    auto loadB = [&](int k0, float* bb) {
        const float* xp0 = Xb + (size_t)(k0 + u0j * 8) * HW + p0 + u0p;
#pragma unroll
        for (int c = 0; c < 8; ++c) bb[c] = xp0[(size_t)c * HW];
        if (u1v) {
            const float* xp1 = Xb + (size_t)(k0 + u1j * 8) * HW + p0 + u1p;
#pragma unroll
            for (int c = 0; c < 8; ++c) bb[8 + c] = xp1[(size_t)c * HW];
        }
    };
    auto writeB = [&](const float* bb) {
        short8 vh, vl;
#pragma unroll
        for (int c = 0; c < 8; ++c) {
            unsigned short h = f2bf(bb[c]);
            vh[c] = (short)h; vl[c] = (short)f2bf(bb[c] - bf2f(h));
        }
        *(short8*)&lB[0][u0p * 40 + u0j * 8] = vh;
        *(short8*)&lB[1][u0p * 40 + u0j * 8] = vl;
        if (u1v) {
#pragma unroll
            for (int c = 0; c < 8; ++c) {
                unsigned short h = f2bf(bb[8 + c]);
                vh[c] = (short)h; vl[c] = (short)f2bf(bb[8 + c] - bf2f(h));
            }
            *(short8*)&lB[0][u1p * 40 + u1j * 8] = vh;
            *(short8*)&lB[1][u1p * 40 + u1j * 8] = vl;
        }
    };
    auto loadA = [&](int k0) {
#pragma unroll
        for (int mi = 0; mi < MI; ++mi) {
            int m = mbase + mi * 16 + li;
            ahi[mi] = *(const short8*)(Whi + (size_t)m * KD + k0 + koff);
            alo[mi] = *(const short8*)(Wlo + (size_t)m * KD + k0 + koff);
        }
    };
    auto domfma = [&]() {
#pragma unroll
        for (int ni = 0; ni < 7; ++ni) {
            int n = ni * 16 + li;
            short8 bhi = *(const short8*)&lB[0][n * 40 + koff];
            short8 blo = *(const short8*)&lB[1][n * 40 + koff];
#pragma unroll
            for (int mi = 0; mi < MI; ++mi) {
                acc[mi][ni] = __builtin_amdgcn_mfma_f32_16x16x32_bf16(ahi[mi], bhi, acc[mi][ni], 0, 0, 0);
                acc[mi][ni] = __builtin_amdgcn_mfma_f32_16x16x32_bf16(ahi[mi], blo, acc[mi][ni], 0, 0, 0);
                acc[mi][ni] = __builtin_amdgcn_mfma_f32_16x16x32_bf16(alo[mi], bhi, acc[mi][ni], 0, 0, 0);
            }
        }
    };

    loadB(0, b0);
    for (int ks = 0; ks < NKS; ks += 2) {
        loadA(ks * 32);
        writeB(b0);
        __syncthreads();
        if (ks + 1 < NKS) loadB((ks + 1) * 32, b1);
        domfma();
        __syncthreads();
        loadA((ks + 1) * 32);
        writeB(b1);
        __syncthreads();
        if (ks + 2 < NKS) loadB((ks + 2) * 32, b0);
        domfma();
        __syncthreads();
    }

#pragma unroll
    for (int mi = 0; mi < MI; ++mi) {
        int m0g = mbase + mi * 16 + ((lane >> 4) << 2);
#pragma unroll
        for (int ni = 0; ni < 7; ++ni) {
            int p = p0 + ni * 16 + li;
#pragma unroll
            for (int r = 0; r < 4; ++r)
                Ob[(size_t)(m0g + r) * HW + p] = acc[mi][ni][r] + bias[m0g + r];
        }
    }
}

// ---------------- fused GRU step (round-5 proven version + T5 setprio) ----------------
__global__ __launch_bounds__(512, 2) void gru_step(
    const ushort_t* __restrict__ hRhi, const ushort_t* __restrict__ hRlo,
    ushort_t* __restrict__ hWhi, ushort_t* __restrict__ hWlo,
    const ushort_t* __restrict__ azh, const ushort_t* __restrict__ azl,
    const ushort_t* __restrict__ ahh, const ushort_t* __restrict__ ahl,
    const float* __restrict__ wxb, float* __restrict__ hs_t, int t)
{
    const int y0 = blockIdx.x, b = blockIdx.y;
    const int tid = threadIdx.x, lane = tid & 63, wv = tid >> 6;
    const int li = lane & 15, koff8 = (lane >> 4) * 8, kq = (lane >> 4) * 4;

    __shared__ ushort_t Hhi[5 * 30 * 72], Hlo[5 * 30 * 72];  // h rows y0-2..y0+2
    __shared__ ushort_t Rhi[3 * 30 * 72], Rlo[3 * 30 * 72];  // r*h rows y0-1..y0+1
    __shared__ float zs[28 * 68];                            // z[col][k]

    {
        const ushort_t* gh = hRhi + (size_t)b * HW * 64;
        const ushort_t* gl = hRlo + (size_t)b * HW * 64;
        for (int e = tid; e < 1200; e += 512) {
            int r = e / 240, rem = e - r * 240;
            int lx = rem >> 3, j = rem & 7;
            int gy = y0 - 2 + r, gx = lx - 1;
            short8 vh = {0,0,0,0,0,0,0,0}, vl = {0,0,0,0,0,0,0,0};
            if (gy >= 0 && gy < 28 && gx >= 0 && gx < 28) {
                size_t go = ((size_t)(gy * 28 + gx)) * 64 + j * 8;
                vh = *(const short8*)(gh + go);
                vl = *(const short8*)(gl + go);
            }
            int lo = (r * 30 + lx) * 72 + j * 8;
            *(short8*)&Hhi[lo] = vh;
            *(short8*)&Hlo[lo] = vl;
        }
        short8 z8 = {0,0,0,0,0,0,0,0};
        for (int e = tid; e < 1620; e += 512) {
            if (e < 810) *(short8*)&Rhi[e * 8] = z8;
            else         *(short8*)&Rlo[(e - 810) * 8] = z8;
        }
    }
    __syncthreads();

    const float* wx = wxb + ((size_t)(b * T_ + t) * K_) * HW;
    const int c0 = li;
    const int c1 = (li < 12) ? 16 + li : 0;

    if (wv < 4) {
        // ---- z gate
        const int kb = wv * 16;
        const ushort_t* Ah = azh + (size_t)(kb + li) * 576;
        const ushort_t* Al = azl + (size_t)(kb + li) * 576;
        floatx4 az[2];
        az[0] = (floatx4){0.f,0.f,0.f,0.f}; az[1] = (floatx4){0.f,0.f,0.f,0.f};
#pragma unroll
        for (int tap = 0; tap < 9; ++tap) {
            const int dy = tap / 3, dx = tap - dy * 3;
#pragma unroll
            for (int ch = 0; ch < 2; ++ch) {
                short8 whi_ = *(const short8*)(Ah + tap * 64 + ch * 32 + koff8);
                short8 wlo_ = *(const short8*)(Al + tap * 64 + ch * 32 + koff8);
                int cb = ch * 32 + koff8;
                int o0 = ((dy + 1) * 30 + c0 + dx) * 72 + cb;
                int o1 = ((dy + 1) * 30 + c1 + dx) * 72 + cb;
                short8 bh0 = *(const short8*)&Hhi[o0];
                short8 bl0 = *(const short8*)&Hlo[o0];
                short8 bh1 = *(const short8*)&Hhi[o1];
                short8 bl1 = *(const short8*)&Hlo[o1];
                az[0] = __builtin_amdgcn_mfma_f32_16x16x32_bf16(whi_, bh0, az[0], 0, 0, 0);
                az[0] = __builtin_amdgcn_mfma_f32_16x16x32_bf16(whi_, bl0, az[0], 0, 0, 0);
                az[0] = __builtin_amdgcn_mfma_f32_16x16x32_bf16(wlo_, bh0, az[0], 0, 0, 0);
                az[1] = __builtin_amdgcn_mfma_f32_16x16x32_bf16(whi_, bh1, az[1], 0, 0, 0);
                az[1] = __builtin_amdgcn_mfma_f32_16x16x32_bf16(whi_, bl1, az[1], 0, 0, 0);
                az[1] = __builtin_amdgcn_mfma_f32_16x16x32_bf16(wlo_, bh1, az[1], 0, 0, 0);
            }
        }
        const int kb4 = kb + kq;
#pragma unroll
        for (int cf = 0; cf < 2; ++cf) {
            int c = cf * 16 + li;
            if (c < 28) {
                floatx4 zv;
#pragma unroll
                for (int r = 0; r < 4; ++r)
                    zv[r] = 1.f / (1.f + __expf(-(wx[(size_t)(kb4 + r) * HW + y0 * 28 + c] + az[cf][r])));
                *(floatx4*)&zs[c * 68 + kb4] = zv;
            }
        }
    } else {
        // ---- r gate rows y0-1..y0+1 -> r*h  (critical path: boost priority)
        const int kb = (wv - 4) * 16;
        const ushort_t* Ah = azh + (size_t)(64 + kb + li) * 576;
        const ushort_t* Al = azl + (size_t)(64 + kb + li) * 576;
        floatx4 ar[3][2];
#pragma unroll
        for (int i = 0; i < 3; ++i) {
            ar[i][0] = (floatx4){0.f,0.f,0.f,0.f};
            ar[i][1] = (floatx4){0.f,0.f,0.f,0.f};
        }
        __builtin_amdgcn_s_setprio(1);
#pragma unroll
        for (int tap = 0; tap < 9; ++tap) {
            const int dy = tap / 3, dx = tap - dy * 3;
#pragma unroll
            for (int ch = 0; ch < 2; ++ch) {
                short8 whi_ = *(const short8*)(Ah + tap * 64 + ch * 32 + koff8);
                short8 wlo_ = *(const short8*)(Al + tap * 64 + ch * 32 + koff8);
                int cb = ch * 32 + koff8;
#pragma unroll
                for (int rr = 0; rr < 3; ++rr) {
                    int o0 = ((rr + dy) * 30 + c0 + dx) * 72 + cb;
                    int o1 = ((rr + dy) * 30 + c1 + dx) * 72 + cb;
                    short8 bh0 = *(const short8*)&Hhi[o0];
                    short8 bl0 = *(const short8*)&Hlo[o0];
                    short8 bh1 = *(const short8*)&Hhi[o1];
                    short8 bl1 = *(const short8*)&Hlo[o1];
                    ar[rr][0] = __builtin_amdgcn_mfma_f32_16x16x32_bf16(whi_, bh0, ar[rr][0], 0, 0, 0);
                    ar[rr][0] = __builtin_amdgcn_mfma_f32_16x16x32_bf16(whi_, bl0, ar[rr][0], 0, 0, 0);
                    ar[rr][0] = __builtin_amdgcn_mfma_f32_16x16x32_bf16(wlo_, bh0, ar[rr][0], 0, 0, 0);
                    ar[rr][1] = __builtin_amdgcn_mfma_f32_16x16x32_bf16(whi_, bh1, ar[rr][1], 0, 0, 0);
                    ar[rr][1] = __builtin_amdgcn_mfma_f32_16x16x32_bf16(whi_, bl1, ar[rr][1], 0, 0, 0);
                    ar[rr][1] = __builtin_amdgcn_mfma_f32_16x16x32_bf16(wlo_, bh1, ar[rr][1], 0, 0, 0);
                }
            }
        }
        __builtin_amdgcn_s_setprio(0);
        const int kb4 = kb + kq;
#pragma unroll
        for (int rr = 0; rr < 3; ++rr) {
            int gy = y0 - 1 + rr;
            if (gy < 0 || gy >= 28) continue;
#pragma unroll
            for (int cf = 0; cf < 2; ++cf) {
                int c = cf * 16 + li;
                if (c >= 28) continue;
                short4v ph = *(const short4v*)&Hhi[((rr + 1) * 30 + c + 1) * 72 + kb4];
                short4v pl = *(const short4v*)&Hlo[((rr + 1) * 30 + c + 1) * 72 + kb4];
                short4v vh, vl;
#pragma unroll
                for (int r = 0; r < 4; ++r) {
                    float rv = 1.f / (1.f + __expf(-(wx[(size_t)(kb4 + r) * HW + gy * 28 + c] + ar[rr][cf][r])));
                    float hv = bf2f((unsigned short)ph[r]) + bf2f((unsigned short)pl[r]);
                    float rh = rv * hv;
                    unsigned short h = f2bf(rh);
                    vh[r] = (short)h; vl[r] = (short)f2bf(rh - bf2f(h));
                }
                *(short4v*)&Rhi[(rr * 30 + c + 1) * 72 + kb4] = vh;
                *(short4v*)&Rlo[(rr * 30 + c + 1) * 72 + kb4] = vl;
            }
        }
    }
    __syncthreads();

    if (wv < 4) {
        // ---- candidate conv + state update
        const int kb = wv * 16;
        const ushort_t* Ah = ahh + (size_t)(kb + li) * 576;
        const ushort_t* Al = ahl + (size_t)(kb + li) * 576;
        floatx4 ac[2];
        ac[0] = (floatx4){0.f,0.f,0.f,0.f}; ac[1] = (floatx4){0.f,0.f,0.f,0.f};
#pragma unroll
        for (int tap = 0; tap < 9; ++tap) {
            const int dy = tap / 3, dx = tap - dy * 3;
#pragma unroll
            for (int ch = 0; ch < 2; ++ch) {
                short8 whi_ = *(const short8*)(Ah + tap * 64 + ch * 32 + koff8);
                short8 wlo_ = *(const short8*)(Al + tap * 64 + ch * 32 + koff8);
                int cb = ch * 32 + koff8;
                int o0 = (dy * 30 + c0 + dx) * 72 + cb;
                int o1 = (dy * 30 + c1 + dx) * 72 + cb;
                short8 bh0 = *(const short8*)&Rhi[o0];
                short8 bl0 = *(const short8*)&Rlo[o0];
                short8 bh1 = *(const short8*)&Rhi[o1];
                short8 bl1 = *(const short8*)&Rlo[o1];
                ac[0] = __builtin_amdgcn_mfma_f32_16x16x32_bf16(whi_, bh0, ac[0], 0, 0, 0);
                ac[0] = __builtin_amdgcn_mfma_f32_16x16x32_bf16(whi_, bl0, ac[0], 0, 0, 0);
                ac[0] = __builtin_amdgcn_mfma_f32_16x16x32_bf16(wlo_, bh0, ac[0], 0, 0, 0);
                ac[1] = __builtin_amdgcn_mfma_f32_16x16x32_bf16(whi_, bh1, ac[1], 0, 0, 0);
                ac[1] = __builtin_amdgcn_mfma_f32_16x16x32_bf16(whi_, bl1, ac[1], 0, 0, 0);
                ac[1] = __builtin_amdgcn_mfma_f32_16x16x32_bf16(wlo_, bh1, ac[1], 0, 0, 0);
            }
        }
        const int kb4 = kb + kq;
        float* hsb = hs_t + (size_t)b * K_ * HW;
#pragma unroll
        for (int cf = 0; cf < 2; ++cf) {
            int c = cf * 16 + li;
            if (c >= 28) continue;
            int p = y0 * 28 + c;
            floatx4 zv = *(const floatx4*)&zs[c * 68 + kb4];
            short4v ph = *(const short4v*)&Hhi[(2 * 30 + c + 1) * 72 + kb4];
            short4v pl = *(const short4v*)&Hlo[(2 * 30 + c + 1) * 72 + kb4];
            short4v vh, vl;
#pragma unroll
            for (int r = 0; r < 4; ++r) {
                int k = kb4 + r;
                float xv = wx[(size_t)k * HW + p] + ac[cf][r];
                float e2 = __expf(2.f * xv);
                float th = 1.f - 2.f / (e2 + 1.f);
                float hp = bf2f((unsigned short)ph[r]) + bf2f((unsigned short)pl[r]);
                float hn = (1.f - zv[r]) * th + zv[r] * hp;
                hsb[(size_t)k * HW + p] = hn;
                unsigned short h = f2bf(hn);
                vh[r] = (short)h; vl[r] = (short)f2bf(hn - bf2f(h));
            }
            size_t o = ((size_t)(b * HW) + p) * 64 + kb4;
            *(short4v*)(hWhi + o) = vh;
            *(short4v*)(hWlo + o) = vl;
        }
    }
}

// ---------------- softmax over k (in place on hs) ----------------
__global__ __launch_bounds__(256) void softmax_k(float* __restrict__ hs)
{
    int q = blockIdx.x;
    int py = blockIdx.y;
    float* base = hs + (size_t)q * K_ * HW;
    for (int p = py * 392 + threadIdx.x; p < (py + 1) * 392 && p < HW; p += 256) {
        float v[64];
        float m = -1e30f;
#pragma unroll
        for (int k = 0; k < 64; ++k) {
            v[k] = base[(size_t)k * HW + p];
            m = fmaxf(m, v[k]);
        }
        float s = 0.f;
#pragma unroll
        for (int k = 0; k < 64; ++k) {
            v[k] = __expf(v[k] - m);
            s += v[k];
        }
        float inv = 1.f / s;
#pragma unroll
        for (int k = 0; k < 64; ++k)
            base[(size_t)k * HW + p] = v[k] * inv;
    }
}

// ---------------- VLAD: per-(b,t) outer-product GEMM + fused a_sum ----------------
__global__ __launch_bounds__(256) void vlad_k(const float* __restrict__ assign,
    const float* __restrict__ xr, float* __restrict__ vladt,
    float* __restrict__ asum_bt)
{
    int dt = blockIdx.x, t = blockIdx.y, b = blockIdx.z;
    int q = t * B_ + b, bt = b * T_ + t, d0 = dt * 64;
    const float* ab = assign + (size_t)q * K_ * HW;
    const float* xb = xr + (size_t)bt * D_ * HW;
    __shared__ float As[16][68];
    __shared__ float Xs[16][68];
    int tx = threadIdx.x & 15, ty = threadIdx.x >> 4;
    float acc[4][4] = {{0.f}};
    float pacc[4] = {0.f, 0.f, 0.f, 0.f};

    for (int p0 = 0; p0 < HW; p0 += 16) {
#pragma unroll
        for (int it = 0; it < 4; ++it) {
            int e = threadIdx.x + it * 256;
            int row = e >> 4, pp = e & 15;
            float av_ = ab[(size_t)row * HW + p0 + pp];
            As[pp][row] = av_;
            if (dt == 0) pacc[it] += av_;
            Xs[pp][row] = xb[(size_t)(d0 + row) * HW + p0 + pp];
        }
        __syncthreads();
#pragma unroll
        for (int pp = 0; pp < 16; ++pp) {
            float4 a = *(const float4*)&As[pp][ty * 4];
            float4 xv = *(const float4*)&Xs[pp][tx * 4];
            float av[4] = {a.x, a.y, a.z, a.w};
            float xvv[4] = {xv.x, xv.y, xv.z, xv.w};
#pragma unroll
            for (int r = 0; r < 4; ++r)
#pragma unroll
                for (int s = 0; s < 4; ++s)
                    acc[r][s] = fmaf(av[r], xvv[s], acc[r][s]);
        }
        __syncthreads();
    }
#pragma unroll
    for (int r = 0; r < 4; ++r) {
        int k = ty * 4 + r;
        float4 o = {acc[r][0], acc[r][1], acc[r][2], acc[r][3]};
        *(float4*)&vladt[((size_t)bt * K_ + k) * D_ + d0 + tx * 4] = o;
    }
    if (dt == 0) {
#pragma unroll
        for (int it = 0; it < 4; ++it) {
            float s = pacc[it];
#pragma unroll
            for (int off = 1; off < 16; off <<= 1) s += __shfl_xor(s, off, 16);
            if (tx == 0) asum_bt[(size_t)bt * 64 + ty + it * 16] = s;
        }
    }
}

// ---------------- reduce over t, subtract a_sum*centers, intra-norm ----------------
__global__ __launch_bounds__(256) void norm1_k(const float* __restrict__ vladt,
    const float* __restrict__ asum_bt, const float* __restrict__ centers,
    float* __restrict__ out)
{
    int bid = blockIdx.x; int b = bid >> 6, k = bid & 63; int d = threadIdx.x;
    float acc = 0.f;
#pragma unroll
    for (int t = 0; t < T_; ++t)
        acc += vladt[(((size_t)b * T_ + t) * K_ + k) * D_ + d];
    float asum = 0.f;
#pragma unroll
    for (int t = 0; t < T_; ++t)
        asum += asum_bt[(size_t)(b * T_ + t) * 64 + k];
    acc -= asum * centers[(size_t)k * D_ + d];
    float ss = block_reduce_sum_256(acc * acc);
    float n = fmaxf(sqrtf(ss), 1e-12f);
    out[((size_t)b * K_ + k) * D_ + d] = acc / n;
}

// ---------------- global L2 norm per b ----------------
__global__ __launch_bounds__(256) void norm2_k(float* __restrict__ out)
{
    int b = blockIdx.x;
    float* v = out + (size_t)b * (K_ * D_);
    float s = 0.f;
    for (int i = threadIdx.x; i < K_ * D_; i += 256) {
        float x = v[i];
        s = fmaf(x, x, s);
    }
    float tot = block_reduce_sum_256(s);
    float n = fmaxf(sqrtf(tot), 1e-12f);
    for (int i = threadIdx.x; i < K_ * D_; i += 256) v[i] = v[i] / n;
}

// ---------------- launch ----------------
extern "C" void kernel_launch(void* const* d_in, const int* in_sizes, int n_in,
                              void* d_out, int out_size, void* d_ws, size_t ws_size,
                              hipStream_t stream)
{
    const float* x       = (const float*)d_in[0];
    const float* redu_w  = (const float*)d_in[1];
    const float* redu_b  = (const float*)d_in[2];
    const float* share_w = (const float*)d_in[3];
    const float* share_b = (const float*)d_in[4];
    const float* Uz      = (const float*)d_in[5];
    const float* Ur      = (const float*)d_in[6];
    const float* Uh      = (const float*)d_in[7];
    const float* centers = (const float*)d_in[8];

    float* ws = (float*)d_ws;
    const size_t SZ_XR   = (size_t)128 * D_ * HW;       // 25,690,112
    const size_t SZ_WXB  = (size_t)128 * K_ * HW;       //  6,422,528
    const size_t SZ_HS   = (size_t)T_ * B_ * K_ * HW;   //  6,422,528
    const size_t SZ_PLANE= (size_t)B_ * K_ * HW;        //    401,408

    float* xr     = ws;
    float* wxb    = xr + SZ_XR;
    float* hs     = wxb + SZ_WXB;
    float* asum_bt= hs + SZ_HS;              // 8192 floats
    float* wsplit = asum_bt + 8192;          // split weights (323,584 floats)
    float* area   = wsplit + 323584;         // union: vladt | GRU split state

    ushort_t* whi = (ushort_t*)wsplit;            // 196608
    ushort_t* wlo = whi + 196608;
    ushort_t* shi = wlo + 196608;                 // 16384
    ushort_t* slo = shi + 16384;
    ushort_t* azh = slo + 16384;                  // 73728
    ushort_t* azl = azh + 73728;
    ushort_t* ahh = azl + 73728;                  // 36864
    ushort_t* ahl = ahh + 36864;

    float* vladt = area;                          // 2,097,152 floats (after GRU)
    ushort_t* st = (ushort_t*)area;               // GRU double-buffered state
    ushort_t* h0hi = st;
    ushort_t* h0lo = st + SZ_PLANE;
    ushort_t* h1hi = st + 2 * SZ_PLANE;
    ushort_t* h1lo = st + 3 * SZ_PLANE;

    hipMemsetAsync(h0hi, 0, 2 * SZ_PLANE * sizeof(ushort_t), stream);

    cvt_weights<<<dim3((D_ * CIN + K_ * D_ + 128 * 576 + 64 * 576 + 255) / 256),
                  256, 0, stream>>>(redu_w, share_w, Uz, Ur, Uh,
                                    whi, wlo, shi, slo, azh, azl, ahh, ahl);

    // 1) channel reduction (split-bf16 MFMA, BM=256: single B-read)
    mfma_conv1x1<256, 256, CIN, 2><<<dim3(7, 1, 128), 256, 0, stream>>>(x, whi, wlo, redu_b, xr);
    // 2) assignment logits
    mfma_conv1x1<64, 64, D_, 4><<<dim3(7, 1, 128), 256, 0, stream>>>(xr, shi, slo, share_b, wxb);

    // 3) ConvGRU: one fused dispatch per timestep (round-5 structure + setprio)
    for (int t = 0; t < T_; ++t) {
        const ushort_t* rh_ = (t & 1) ? h1hi : h0hi;
        const ushort_t* rl_ = (t & 1) ? h1lo : h0lo;
        ushort_t* wh_ = (t & 1) ? h0hi : h1hi;
        ushort_t* wl_ = (t & 1) ? h0lo : h1lo;
        gru_step<<<dim3(28, 8), 512, 0, stream>>>(rh_, rl_, wh_, wl_,
                                                  azh, azl, ahh, ahl,
                                                  wxb, hs + (size_t)t * SZ_PLANE, t);
    }

    // 4) softmax over centers
    softmax_k<<<dim3(128, 2), 256, 0, stream>>>(hs);

    // 5) VLAD aggregation (+fused a_sum) + norms
    vlad_k<<<dim3(4, 16, 8), 256, 0, stream>>>(hs, xr, vladt, asum_bt);
    norm1_k<<<512, 256, 0, stream>>>(vladt, asum_bt, centers, (float*)d_out);
    norm2_k<<<8, 256, 0, stream>>>((float*)d_out);
}